// Round 2
// baseline (1814.147 us; speedup 1.0000x reference)
//
#include <hip/hip_runtime.h>

#define NN 100000
#define NE 3200000
#define EP (NE + NN)      // edges incl. self loops
#define H 32
#define EMBD 16
#define NEMB 141
#define NEG_SLOPE 0.2f

// CAS-based float atomic max (init with finite -3e38f)
__device__ __forceinline__ void atomicMaxF(float* addr, float val) {
    int old = __float_as_int(*addr);
    while (__int_as_float(old) < val) {
        int prev = atomicCAS((int*)addr, old, __float_as_int(val));
        if (prev == old) break;
        old = prev;
    }
}

// scal[0] = sum_j We1[j]*ae1[j]; scal[1] = same for layer 2 (EDGE_DIM==1
// collapses (ea@We)@ae to ea * scal)
__global__ void k_scal(const float* We1, const float* ae1,
                       const float* We2, const float* ae2, float* scal) {
    if (threadIdx.x == 0) {
        float c1 = 0.f, c2 = 0.f;
        for (int j = 0; j < H; j++) {
            c1 += We1[j] * ae1[j];
            c2 += We2[j] * ae2[j];
        }
        scal[0] = c1; scal[1] = c2;
    }
}

// tabH[r][j] = (emb[r] @ W1)[j]  for the 141 distinct embedding rows;
// tabS[r] = tabH[r]@as1, tabD[r] = tabH[r]@ad1
__global__ void k_tab(const float* __restrict__ emb, const float* __restrict__ W1,
                      const float* __restrict__ as1, const float* __restrict__ ad1,
                      float* tabH, float* tabS, float* tabD) {
    int r = blockIdx.x;            // 0..140
    int j = threadIdx.x;           // 0..31
    float acc = 0.f;
    #pragma unroll
    for (int k = 0; k < EMBD; k++) acc += emb[r * EMBD + k] * W1[k * H + j];
    tabH[r * H + j] = acc;
    float s = acc * as1[j];
    float d = acc * ad1[j];
    #pragma unroll
    for (int off = 16; off > 0; off >>= 1) {
        s += __shfl_down(s, off, 32);
        d += __shfl_down(d, off, 32);
    }
    if (j == 0) { tabS[r] = s; tabD[r] = d; }
}

__global__ void k_zero(float* p, int n) {
    int i = blockIdx.x * blockDim.x + threadIdx.x;
    if (i < n) p[i] = 0.f;
}

__global__ void k_loopsum(const int* __restrict__ dst, const float* __restrict__ ea,
                          float* sums, float* cnt) {
    int e = blockIdx.x * blockDim.x + threadIdx.x;
    if (e < NE) {
        int d = dst[e];
        atomicAdd(&sums[d], ea[e]);
        atomicAdd(&cnt[d], 1.f);
    }
}

// per-node init for layer 1: loop_attr, hs/hd via tables, amax/denom/agg init
__global__ void k_node1(const int* __restrict__ x_idx,
                        const float* __restrict__ tabS, const float* __restrict__ tabD,
                        const float* __restrict__ sums, const float* __restrict__ cnt,
                        float* loop_attr, float* hs, float* hd,
                        float* amax, float* denom, float* agg) {
    int i = blockIdx.x * blockDim.x + threadIdx.x;
    if (i >= NN) return;
    loop_attr[i] = sums[i] / fmaxf(cnt[i], 1.f);
    int idx = x_idx[i];
    hs[i] = tabS[idx];
    hd[i] = tabD[idx];
    amax[i] = -3.0e38f;
    denom[i] = 0.f;
    #pragma unroll
    for (int j = 0; j < H; j++) agg[i * H + j] = 0.f;
}

// edge pass A: alpha = leaky_relu(hs[s]+hd[d]+scal*a) -> atomic max into amax[dst]
__global__ void k_eA(const int* __restrict__ src, const int* __restrict__ dst,
                     const float* __restrict__ ea, const float* __restrict__ loop_attr,
                     const float* __restrict__ hs, const float* __restrict__ hd,
                     const float* __restrict__ scal, int si, float* amax) {
    int e = blockIdx.x * blockDim.x + threadIdx.x;
    if (e >= EP) return;
    int s, d; float a;
    if (e < NE) { s = src[e]; d = dst[e]; a = ea[e]; }
    else        { s = e - NE; d = s;      a = loop_attr[s]; }
    float al = hs[s] + hd[d] + scal[si] * a;
    al = (al > 0.f) ? al : NEG_SLOPE * al;
    atomicMaxF(&amax[d], al);
}

// edge pass B (32 lanes/edge): ex = exp(alpha - amax[dst]);
// denom[dst] += ex (lane 0); agg[dst][j] += ex * h_src[j]
__global__ void k_eB(const int* __restrict__ src, const int* __restrict__ dst,
                     const float* __restrict__ ea, const float* __restrict__ loop_attr,
                     const float* __restrict__ hs, const float* __restrict__ hd,
                     const float* __restrict__ scal, int si,
                     const float* __restrict__ amax,
                     const float* __restrict__ hsrc, const int* __restrict__ xi,
                     float* denom, float* agg) {
    long long tid = (long long)blockIdx.x * blockDim.x + threadIdx.x;
    int e = (int)(tid >> 5);
    int j = (int)(tid & 31);
    if (e >= EP) return;
    int s, d; float a;
    if (e < NE) { s = src[e]; d = dst[e]; a = ea[e]; }
    else        { s = e - NE; d = s;      a = loop_attr[s]; }
    float al = hs[s] + hd[d] + scal[si] * a;
    al = (al > 0.f) ? al : NEG_SLOPE * al;
    float z = fminf(al - amax[d], 0.f);   // clamp: exp can never overflow
    float ex = __expf(z);
    if (j == 0) atomicAdd(&denom[d], ex);
    float hv = xi ? hsrc[xi[s] * H + j] : hsrc[s * H + j];
    atomicAdd(&agg[d * H + j], ex * hv);
}

// between layers: x = relu(agg/denom + b1); h = x@W2; hs/hd; re-init state
__global__ void k_node2(const float* __restrict__ b1, const float* __restrict__ W2,
                        const float* __restrict__ as2, const float* __restrict__ ad2,
                        float* h, float* hs, float* hd,
                        float* amax, float* denom, float* agg) {
    __shared__ float Ws[H * H];
    __shared__ float asS[H], adS[H], bS[H];
    int t = threadIdx.x;
    for (int k = t; k < H * H; k += blockDim.x) Ws[k] = W2[k];
    if (t < H) { asS[t] = as2[t]; adS[t] = ad2[t]; bS[t] = b1[t]; }
    __syncthreads();
    int i = blockIdx.x * blockDim.x + t;
    if (i >= NN) return;
    float dn = denom[i] + 1e-16f;
    float v[H];
    #pragma unroll
    for (int j = 0; j < H; j++) {
        float u = agg[i * H + j] / dn + bS[j];
        v[j] = (u > 0.f) ? u : 0.f;
        agg[i * H + j] = 0.f;
    }
    float s = 0.f, dd = 0.f;
    #pragma unroll
    for (int j = 0; j < H; j++) {
        float acc = 0.f;
        #pragma unroll
        for (int k = 0; k < H; k++) acc += v[k] * Ws[k * H + j];
        h[i * H + j] = acc;
        s += acc * asS[j];
        dd += acc * adS[j];
    }
    hs[i] = s; hd[i] = dd;
    amax[i] = -3.0e38f;
    denom[i] = 0.f;
}

// head: out = (agg/denom + b2) @ Wl + bl   (float32 output)
__global__ void k_final(const float* __restrict__ b2, const float* __restrict__ Wl,
                        const float* __restrict__ bl,
                        const float* __restrict__ denom, const float* __restrict__ agg,
                        float* out) {
    __shared__ float wS[H], bS[H];
    int t = threadIdx.x;
    if (t < H) { wS[t] = Wl[t]; bS[t] = b2[t]; }
    __syncthreads();
    int i = blockIdx.x * blockDim.x + t;
    if (i >= NN) return;
    float dn = denom[i] + 1e-16f;
    float acc = bl[0];
    #pragma unroll
    for (int j = 0; j < H; j++) acc += (agg[i * H + j] / dn + bS[j]) * wS[j];
    out[i] = acc;
}

extern "C" void kernel_launch(void* const* d_in, const int* in_sizes, int n_in,
                              void* d_out, int out_size, void* d_ws, size_t ws_size,
                              hipStream_t stream) {
    const int*   x_idx = (const int*)d_in[0];
    const int*   src   = (const int*)d_in[1];   // edge_index row 0
    const int*   dst   = src + NE;              // edge_index row 1
    const float* ea    = (const float*)d_in[2];
    // d_in[3] = emb
    const float* emb = (const float*)d_in[3];
    const float* W1  = (const float*)d_in[4];
    const float* as1 = (const float*)d_in[5];
    const float* ad1 = (const float*)d_in[6];
    const float* We1 = (const float*)d_in[7];
    const float* ae1 = (const float*)d_in[8];
    const float* b1  = (const float*)d_in[9];
    const float* W2  = (const float*)d_in[10];
    const float* as2 = (const float*)d_in[11];
    const float* ad2 = (const float*)d_in[12];
    const float* We2 = (const float*)d_in[13];
    const float* ae2 = (const float*)d_in[14];
    const float* b2  = (const float*)d_in[15];
    const float* Wl  = (const float*)d_in[16];
    const float* bl  = (const float*)d_in[17];
    float* out = (float*)d_out;

    // workspace layout (floats), total = 8192 + 69*NN = 6,908,192 fl = 27.6 MB
    float* ws   = (float*)d_ws;
    float* scal = ws;                 // 2
    float* tabS = ws + 8;             // 141
    float* tabD = ws + 160;           // 141
    float* tabH = ws + 320;           // 141*32 = 4512
    float* base = ws + 8192;
    float* loop_attr = base;                  // N
    float* hs        = base + (size_t)NN;     // N
    float* hd        = base + 2 * (size_t)NN; // N
    float* amax      = base + 3 * (size_t)NN; // N
    float* denom     = base + 4 * (size_t)NN; // N
    float* h         = base + 5 * (size_t)NN; // 32N (first 2N alias sums/cnt)
    float* agg       = base + 37 * (size_t)NN;// 32N
    float* sums = h;            // dead before k_node2 writes h
    float* cnt  = h + (size_t)NN;

    const int B = 256;
    int gN   = (NN + B - 1) / B;
    int g2N  = (2 * NN + B - 1) / B;
    int gE   = (NE + B - 1) / B;
    int gEP  = (EP + B - 1) / B;
    int gEP32 = (int)(((long long)EP * H + B - 1) / B);

    k_scal<<<1, 64, 0, stream>>>(We1, ae1, We2, ae2, scal);
    k_tab<<<NEMB, 32, 0, stream>>>(emb, W1, as1, ad1, tabH, tabS, tabD);
    k_zero<<<g2N, B, 0, stream>>>(sums, 2 * NN);
    k_loopsum<<<gE, B, 0, stream>>>(dst, ea, sums, cnt);
    k_node1<<<gN, B, 0, stream>>>(x_idx, tabS, tabD, sums, cnt,
                                  loop_attr, hs, hd, amax, denom, agg);
    // layer 1 (h gathered via tabH[x_idx[s]])
    k_eA<<<gEP, B, 0, stream>>>(src, dst, ea, loop_attr, hs, hd, scal, 0, amax);
    k_eB<<<gEP32, B, 0, stream>>>(src, dst, ea, loop_attr, hs, hd, scal, 0,
                                  amax, tabH, x_idx, denom, agg);
    // layer 2
    k_node2<<<gN, B, 0, stream>>>(b1, W2, as2, ad2, h, hs, hd, amax, denom, agg);
    k_eA<<<gEP, B, 0, stream>>>(src, dst, ea, loop_attr, hs, hd, scal, 1, amax);
    k_eB<<<gEP32, B, 0, stream>>>(src, dst, ea, loop_attr, hs, hd, scal, 1,
                                  amax, h, (const int*)nullptr, denom, agg);
    // head
    k_final<<<gN, B, 0, stream>>>(b2, Wl, bl, denom, agg, out);
}

// Round 3
// 655.617 us; speedup vs baseline: 2.7671x; 2.7671x over previous
//
#include <hip/hip_runtime.h>

#define NN 100000
#define NE 3200000
#define H 32
#define EMBD 16
#define NEMB 141
#define NEG_SLOPE 0.2f
#define NB 98            // ceil(NN/1024) scan blocks

// scal[0] = sum_j We1[j]*ae1[j]; scal[1] = layer 2 (EDGE_DIM==1 collapses
// (ea@We)@ae to ea * scal)
__global__ void k_scal(const float* We1, const float* ae1,
                       const float* We2, const float* ae2, float* scal) {
    if (threadIdx.x == 0) {
        float c1 = 0.f, c2 = 0.f;
        for (int j = 0; j < H; j++) {
            c1 += We1[j] * ae1[j];
            c2 += We2[j] * ae2[j];
        }
        scal[0] = c1; scal[1] = c2;
    }
}

// tabH[r][j] = (emb[r]@W1)[j] for the 141 distinct rows; tabS/tabD = dots
__global__ void k_tab(const float* __restrict__ emb, const float* __restrict__ W1,
                      const float* __restrict__ as1, const float* __restrict__ ad1,
                      float* tabH, float* tabS, float* tabD) {
    int r = blockIdx.x, j = threadIdx.x;
    float acc = 0.f;
    #pragma unroll
    for (int k = 0; k < EMBD; k++) acc += emb[r * EMBD + k] * W1[k * H + j];
    tabH[r * H + j] = acc;
    float s = acc * as1[j];
    float d = acc * ad1[j];
    #pragma unroll
    for (int off = 16; off > 0; off >>= 1) {
        s += __shfl_down(s, off, 32);
        d += __shfl_down(d, off, 32);
    }
    if (j == 0) { tabS[r] = s; tabD[r] = d; }
}

__global__ void k_zero_i(int* p, int n) {
    int i = blockIdx.x * blockDim.x + threadIdx.x;
    if (i < n) p[i] = 0;
}

__global__ void k_deg(const int* __restrict__ dst, int* deg) {
    int e = blockIdx.x * blockDim.x + threadIdx.x;
    if (e < NE) atomicAdd(&deg[dst[e]], 1);
}

// 3-kernel exclusive scan of deg -> off
__global__ void k_scanA(const int* __restrict__ deg, int* off, int* bsum) {
    __shared__ int sh[1024];
    int t = threadIdx.x;
    int i = blockIdx.x * 1024 + t;
    int v = (i < NN) ? deg[i] : 0;
    sh[t] = v; __syncthreads();
    for (int s = 1; s < 1024; s <<= 1) {
        int x = (t >= s) ? sh[t - s] : 0;
        __syncthreads();
        sh[t] += x;
        __syncthreads();
    }
    if (i < NN) off[i] = sh[t] - v;
    if (t == 1023) bsum[blockIdx.x] = sh[1023];
}

__global__ void k_scanB(int* bsum) {
    __shared__ int sh[128];
    int t = threadIdx.x;
    int v = (t < NB) ? bsum[t] : 0;
    sh[t] = v; __syncthreads();
    for (int s = 1; s < 128; s <<= 1) {
        int x = (t >= s) ? sh[t - s] : 0;
        __syncthreads();
        sh[t] += x;
        __syncthreads();
    }
    if (t < NB) bsum[t] = sh[t] - v;
}

__global__ void k_scanC(int* off, const int* __restrict__ bsum) {
    int i = blockIdx.x * blockDim.x + threadIdx.x;
    if (i < NN) off[i] += bsum[i >> 10];
}

// counting-sort edges by dst: es[p]=src, ef[p]=edge_attr
__global__ void k_scatter(const int* __restrict__ src, const int* __restrict__ dst,
                          const float* __restrict__ ea,
                          const int* __restrict__ off, int* fill,
                          int* es, float* ef) {
    int e = blockIdx.x * blockDim.x + threadIdx.x;
    if (e >= NE) return;
    int d = dst[e];
    int p = off[d] + atomicAdd(&fill[d], 1);
    es[p] = src[e];
    ef[p] = ea[e];
}

// layer-1 per-node scalars via tables
__global__ void k_node1(const int* __restrict__ x_idx,
                        const float* __restrict__ tabS, const float* __restrict__ tabD,
                        float* hs, float* hd) {
    int i = blockIdx.x * blockDim.x + threadIdx.x;
    if (i >= NN) return;
    int idx = x_idx[i];
    hs[i] = tabS[idx];
    hd[i] = tabD[idx];
}

// Per-node GAT aggregation, 32 lanes/node, no atomics.
// MODE 0: h rows via tabH[xi[s]]; epilogue x1 = relu(acc/den + b1) -> outp[node*32+lane]
// MODE 1: h rows via hsrc[s];    epilogue out[node] = sum_j(acc/den + b2)*Wl + bl
template<int MODE>
__global__ void k_agg(const int* __restrict__ off, const int* __restrict__ deg,
                      const int* __restrict__ es, const float* __restrict__ ef,
                      const float* __restrict__ hs, const float* __restrict__ hd,
                      const float* __restrict__ scal,
                      const float* __restrict__ hsrc, const int* __restrict__ xi,
                      const float* __restrict__ bias,
                      const float* __restrict__ Wl, const float* __restrict__ bl,
                      float* outp) {
    int lane = threadIdx.x & 31;
    int node = (blockIdx.x * blockDim.x + threadIdx.x) >> 5;
    if (node >= NN) return;
    int beg = off[node];
    int dg  = deg[node];
    int end = beg + dg;
    float sc  = scal[MODE];
    float hdi = hd[node];

    // pass 1: loop_attr sum + alpha max (lanes parallel over edges)
    float suma = 0.f, mloc = -3.0e38f;
    for (int k = beg + lane; k < end; k += 32) {
        float a = ef[k];
        suma += a;
        float al = hs[es[k]] + hdi + sc * a;
        al = (al > 0.f) ? al : NEG_SLOPE * al;
        mloc = fmaxf(mloc, al);
    }
    #pragma unroll
    for (int o = 16; o > 0; o >>= 1) {
        suma += __shfl_xor(suma, o, 32);
        mloc  = fmaxf(mloc, __shfl_xor(mloc, o, 32));
    }
    float la = suma / (float)((dg > 1) ? dg : 1);       // self-loop attr (mean)
    float alself = hs[node] + hdi + sc * la;
    alself = (alself > 0.f) ? alself : NEG_SLOPE * alself;
    float m = fmaxf(mloc, alself);

    // pass 2: exp lane-parallel, then shfl-broadcast into feature-parallel FMA
    float exs = __expf(alself - m);
    float hvself = (MODE == 0) ? hsrc[xi[node] * H + lane] : hsrc[node * H + lane];
    float acc  = exs * hvself;
    float denp = 0.f;
    for (int base = beg; base < end; base += 32) {
        int kk = base + lane;
        float ex = 0.f;
        int s = 0;
        if (kk < end) {
            s = es[kk];
            float al = hs[s] + hdi + sc * ef[kk];
            al = (al > 0.f) ? al : NEG_SLOPE * al;
            ex = __expf(al - m);
        }
        denp += ex;
        #pragma unroll
        for (int t = 0; t < 32; t++) {
            float ext = __shfl(ex, t, 32);
            int   st  = __shfl(s, t, 32);
            float hv = (MODE == 0) ? hsrc[xi[st] * H + lane] : hsrc[st * H + lane];
            acc += ext * hv;     // ext==0 for padded slots -> no-op
        }
    }
    #pragma unroll
    for (int o = 16; o > 0; o >>= 1) denp += __shfl_xor(denp, o, 32);
    float den = denp + exs + 1e-16f;
    float u = acc / den + bias[lane];
    if (MODE == 0) {
        outp[node * H + lane] = fmaxf(u, 0.f);          // relu between layers
    } else {
        float term = u * Wl[lane];
        #pragma unroll
        for (int o = 16; o > 0; o >>= 1) term += __shfl_xor(term, o, 32);
        if (lane == 0) outp[node] = term + bl[0];
    }
}

// h2 = x1 @ W2 (in place on hbuf), hs2/hd2
__global__ void k_node2(const float* __restrict__ W2, const float* __restrict__ as2,
                        const float* __restrict__ ad2,
                        float* hbuf, float* hs, float* hd) {
    __shared__ float Ws[H * H];
    __shared__ float asS[H], adS[H];
    int t = threadIdx.x;
    for (int k = t; k < H * H; k += blockDim.x) Ws[k] = W2[k];
    if (t < H) { asS[t] = as2[t]; adS[t] = ad2[t]; }
    __syncthreads();
    int i = blockIdx.x * blockDim.x + t;
    if (i >= NN) return;
    float v[H];
    #pragma unroll
    for (int j = 0; j < H; j++) v[j] = hbuf[i * H + j];
    float s = 0.f, dd = 0.f;
    #pragma unroll
    for (int j = 0; j < H; j++) {
        float acc = 0.f;
        #pragma unroll
        for (int k = 0; k < H; k++) acc += v[k] * Ws[k * H + j];
        hbuf[i * H + j] = acc;
        s += acc * asS[j];
        dd += acc * adS[j];
    }
    hs[i] = s; hd[i] = dd;
}

extern "C" void kernel_launch(void* const* d_in, const int* in_sizes, int n_in,
                              void* d_out, int out_size, void* d_ws, size_t ws_size,
                              hipStream_t stream) {
    const int*   x_idx = (const int*)d_in[0];
    const int*   src   = (const int*)d_in[1];   // edge_index row 0
    const int*   dst   = src + NE;              // edge_index row 1
    const float* ea    = (const float*)d_in[2];
    const float* emb = (const float*)d_in[3];
    const float* W1  = (const float*)d_in[4];
    const float* as1 = (const float*)d_in[5];
    const float* ad1 = (const float*)d_in[6];
    const float* We1 = (const float*)d_in[7];
    const float* ae1 = (const float*)d_in[8];
    const float* b1  = (const float*)d_in[9];
    const float* W2  = (const float*)d_in[10];
    const float* as2 = (const float*)d_in[11];
    const float* ad2 = (const float*)d_in[12];
    const float* We2 = (const float*)d_in[13];
    const float* ae2 = (const float*)d_in[14];
    const float* b2  = (const float*)d_in[15];
    const float* Wl  = (const float*)d_in[16];
    const float* bl  = (const float*)d_in[17];
    float* out = (float*)d_out;

    // workspace (4-byte elems): header 8192 | hs N | hd N | deg N | fill N |
    // off N | bsum 128 | es NE | ef NE | hbuf 32N   -> ~40.4 MB total
    float* ws   = (float*)d_ws;
    float* scal = ws;                  // 2
    float* tabS = ws + 8;              // 141
    float* tabD = ws + 256;            // 141
    float* tabH = ws + 512;            // 4512
    size_t base = 8192;
    float* hs   = ws + base;                       // N
    float* hd   = ws + base + (size_t)NN;          // N
    int*   deg  = (int*)(ws + base + 2 * (size_t)NN);  // N
    int*   fill = (int*)(ws + base + 3 * (size_t)NN);  // N (contiguous w/ deg)
    int*   off  = (int*)(ws + base + 4 * (size_t)NN);  // N
    int*   bsum = (int*)(ws + base + 5 * (size_t)NN);  // 128
    int*   es   = (int*)(ws + base + 5 * (size_t)NN + 128);   // NE
    float* ef   = (float*)(es + (size_t)NE);                  // NE
    float* hbuf = ef + (size_t)NE;                            // 32N

    const int B = 256;
    int gN  = (NN + B - 1) / B;
    int g2N = (2 * NN + B - 1) / B;
    int gE  = (NE + B - 1) / B;
    int gA  = (NN * H + B - 1) / B;   // 32 lanes per node

    k_scal<<<1, 64, 0, stream>>>(We1, ae1, We2, ae2, scal);
    k_tab<<<NEMB, 32, 0, stream>>>(emb, W1, as1, ad1, tabH, tabS, tabD);
    // CSR build (deg & fill are contiguous -> one zero kernel)
    k_zero_i<<<g2N, B, 0, stream>>>(deg, 2 * NN);
    k_deg<<<gE, B, 0, stream>>>(dst, deg);
    k_scanA<<<NB, 1024, 0, stream>>>(deg, off, bsum);
    k_scanB<<<1, 128, 0, stream>>>(bsum);
    k_scanC<<<gN, B, 0, stream>>>(off, bsum);
    k_scatter<<<gE, B, 0, stream>>>(src, dst, ea, off, fill, es, ef);
    // layer 1
    k_node1<<<gN, B, 0, stream>>>(x_idx, tabS, tabD, hs, hd);
    k_agg<0><<<gA / 1, B, 0, stream>>>(off, deg, es, ef, hs, hd, scal,
                                       tabH, x_idx, b1, nullptr, nullptr, hbuf);
    // layer 2
    k_node2<<<gN, B, 0, stream>>>(W2, as2, ad2, hbuf, hs, hd);
    k_agg<1><<<gA / 1, B, 0, stream>>>(off, deg, es, ef, hs, hd, scal,
                                       hbuf, nullptr, b2, Wl, bl, out);
}